// Round 6
// baseline (467.811 us; speedup 1.0000x reference)
//
#include <hip/hip_runtime.h>
#include <stdint.h>

typedef unsigned short u16;
typedef __attribute__((ext_vector_type(8))) short bf16x8;
typedef __attribute__((ext_vector_type(4))) float f32x4;

#define S_LEN 4096
#define HID_DIM 2304
#define QKV_N 4096
#define AO_N 2048
#define HD 256
#define WIN 1024
#define QSCALE 0.0625f

static __device__ __forceinline__ u16 f2bf(float f) {
  union { float f; uint32_t u; } v; v.f = f;
  return (u16)((v.u + 0x7FFFu + ((v.u >> 16) & 1u)) >> 16);
}
static __device__ __forceinline__ float bf2f(u16 h) {
  union { uint32_t u; float f; } v; v.u = ((uint32_t)h) << 16;
  return v.f;
}

static __device__ __forceinline__ void gld16(const void* src, void* dst) {
  __builtin_amdgcn_global_load_lds((const __attribute__((address_space(1))) void*)src,
                                   (__attribute__((address_space(3))) void*)dst, 16, 0, 0);
}

#define BAR() __builtin_amdgcn_s_barrier()
#define LG0() asm volatile("s_waitcnt lgkmcnt(0)" ::: "memory")
#define VM4() asm volatile("s_waitcnt vmcnt(4)" ::: "memory")
#define VM2() asm volatile("s_waitcnt vmcnt(2)" ::: "memory")
#define VM0() asm volatile("s_waitcnt vmcnt(0)" ::: "memory")
#define PRIO1() __builtin_amdgcn_s_setprio(1)
#define PRIO0() __builtin_amdgcn_s_setprio(0)

// ---------------- fp32 -> bf16 elementwise ----------------
__global__ __launch_bounds__(256) void k_cvt_bf16(const float* __restrict__ in,
                                                  u16* __restrict__ out, int n) {
  int i = (blockIdx.x * 256 + threadIdx.x) * 4;
  if (i >= n) return;
  float4 v = *(const float4*)(in + i);
  uint64_t p = (uint64_t)f2bf(v.x) | ((uint64_t)f2bf(v.y) << 16)
             | ((uint64_t)f2bf(v.z) << 32) | ((uint64_t)f2bf(v.w) << 48);
  *(uint64_t*)(out + i) = p;
}

// in: fp32 [R][C] row-major; out bf16: out[(row_off + c)*out_stride + r] = in[r][c]
__global__ __launch_bounds__(256) void k_transpose_cvt(const float* __restrict__ in, int C,
                                                       u16* __restrict__ out, int out_stride,
                                                       int row_off) {
  __shared__ float tile[32][33];
  int c0 = blockIdx.x * 32, r0 = blockIdx.y * 32;
  int tx = threadIdx.x & 31, ty = threadIdx.x >> 5;
#pragma unroll
  for (int i = 0; i < 4; i++)
    tile[ty + i * 8][tx] = in[(size_t)(r0 + ty + i * 8) * C + c0 + tx];
  __syncthreads();
#pragma unroll
  for (int i = 0; i < 4; i++)
    out[(size_t)(row_off + c0 + ty + i * 8) * out_stride + r0 + tx] = f2bf(tile[tx][ty + i * 8]);
}

// ---------------- bf16 transpose of V block of qkv -> vt[kv*256 + d][s] ----------------
__global__ __launch_bounds__(256) void k_vtrans(const u16* __restrict__ qkv,
                                                u16* __restrict__ vtout) {
  __shared__ u16 tile[32][33];
  int c0 = blockIdx.x * 32, s0 = blockIdx.y * 32;
  int tx = threadIdx.x & 31, ty = threadIdx.x >> 5;
#pragma unroll
  for (int i = 0; i < 4; i++)
    tile[ty + i * 8][tx] = qkv[(size_t)(s0 + ty + i * 8) * QKV_N + 3072 + c0 + tx];
  __syncthreads();
#pragma unroll
  for (int i = 0; i < 4; i++)
    vtout[(size_t)(c0 + ty + i * 8) * S_LEN + s0 + tx] = tile[tx][ty + i * 8];
}

// ---------------- bf16 GEMM v3: 256x256, BK=64, true 8-phase (m201 structure) ------------
// 8 waves (2Mx4N) with INTERLEAVED tiling: A row(m)=m*32+wr*16+l15, B row(n)=n*64+wc*16+l15
// so phase operands live in one half-tile. Per K-tile: 4 phases x {ds_reads; stage one
// half-tile of tile t+1 (2 gld16, pre-swizzled src); barrier; lgkm0; prio1; 16 MFMA; prio0;
// counted vmcnt before closing barrier}. Stage order Ah0,Bh0,Bh1,Ah1 = consumption order;
// steady-state vmcnt(4), never drains. LDS 2dbuf x (A+B) 64KB = 128KB.
template <int OUT_BF16>
__global__ __launch_bounds__(512, 2) void k_gemm8p(const u16* __restrict__ A,
                                                   const u16* __restrict__ Bt,
                                                   void* __restrict__ Cout,
                                                   int M, int N, int K) {
  __shared__ u16 sA[2][256 * 64];
  __shared__ u16 sB[2][256 * 64];
  const int t = threadIdx.x, lane = t & 63, wave = t >> 6;
  const int wr = wave >> 2, wc = wave & 3;
  const int l15 = lane & 15, l4 = lane >> 4;
  const int nbn = N >> 8;
  const int cpx = gridDim.x >> 3;
  const int wg = ((int)blockIdx.x & 7) * cpx + ((int)blockIdx.x >> 3);  // bijective XCD swz
  const int bm = wg / nbn, bn = wg % nbn;
  const int NT = K >> 6;
  // staging lane map: half-tile = 128 rows x 128B; per gld16 a wave covers 8 rows x 128B;
  // lane -> row = lane>>3, slot = lane&7; src slot pre-swizzled (involution slot^(row&7))
  const int srow = lane >> 3;
  const int sslot = ((lane & 7) ^ srow) * 8;
  const u16* Abase = A + (size_t)(bm * 256) * K;
  const u16* Bbase = Bt + (size_t)(bn * 256) * K;
  f32x4 acc[8][4] = {};
  bf16x8 aF[4][2], b01[2][2], b23[2][2];

#define STG_A(BUF, HALF, KT) do {                                                 \
    _Pragma("unroll")                                                             \
    for (int c_ = 0; c_ < 2; c_++) {                                              \
      int rb_ = (HALF) * 128 + (wave * 2 + c_) * 8;                               \
      gld16(Abase + (size_t)(rb_ + srow) * K + ((KT) << 6) + sslot,               \
            &sA[BUF][rb_ * 64]);                                                  \
    }                                                                             \
  } while (0)
#define STG_B(BUF, HALF, KT) do {                                                 \
    _Pragma("unroll")                                                             \
    for (int c_ = 0; c_ < 2; c_++) {                                              \
      int rb_ = (HALF) * 128 + (wave * 2 + c_) * 8;                               \
      gld16(Bbase + (size_t)(rb_ + srow) * K + ((KT) << 6) + sslot,               \
            &sB[BUF][rb_ * 64]);                                                  \
    }                                                                             \
  } while (0)
// LDS read with matching XOR swizzle; row&7 == l15&7 for all frag rows
#define LDA(BUF, M_, KK)                                                          \
  (*(const bf16x8*)&sA[BUF][((M_) * 32 + wr * 16 + l15) * 64 +                    \
                            ((((KK) << 2) + l4) ^ (l15 & 7)) * 8])
#define LDB(BUF, N_, KK)                                                          \
  (*(const bf16x8*)&sB[BUF][((N_) * 64 + wc * 16 + l15) * 64 +                    \
                            ((((KK) << 2) + l4) ^ (l15 & 7)) * 8])

#define P1_LOADS(b_) do {                                                         \
    _Pragma("unroll") for (int m_ = 0; m_ < 4; m_++)                              \
      _Pragma("unroll") for (int k_ = 0; k_ < 2; k_++)                            \
        aF[m_][k_] = LDA(b_, m_, k_);                                             \
    _Pragma("unroll") for (int n_ = 0; n_ < 2; n_++)                              \
      _Pragma("unroll") for (int k_ = 0; k_ < 2; k_++)                            \
        b01[n_][k_] = LDB(b_, n_, k_);                                            \
  } while (0)
#define P2_LOADS(b_) do {                                                         \
    _Pragma("unroll") for (int n_ = 0; n_ < 2; n_++)                              \
      _Pragma("unroll") for (int k_ = 0; k_ < 2; k_++)                            \
        b23[n_][k_] = LDB(b_, n_ + 2, k_);                                        \
  } while (0)
#define P3_LOADS(b_) do {                                                         \
    _Pragma("unroll") for (int m_ = 0; m_ < 4; m_++)                              \
      _Pragma("unroll") for (int k_ = 0; k_ < 2; k_++)                            \
        aF[m_][k_] = LDA(b_, m_ + 4, k_);                                         \
  } while (0)
#define MFMA16(MOFF, NOFF, BREG) do {                                             \
    _Pragma("unroll") for (int m_ = 0; m_ < 4; m_++)                              \
      _Pragma("unroll") for (int n_ = 0; n_ < 2; n_++)                            \
        _Pragma("unroll") for (int k_ = 0; k_ < 2; k_++)                          \
          acc[m_ + MOFF][n_ + NOFF] = __builtin_amdgcn_mfma_f32_16x16x32_bf16(    \
              aF[m_][k_], BREG[n_][k_], acc[m_ + MOFF][n_ + NOFF], 0, 0, 0);      \
  } while (0)

  // prologue: stage tile 0 in consumption order
  STG_A(0, 0, 0);
  STG_B(0, 0, 0);
  STG_B(0, 1, 0);
  STG_A(0, 1, 0);
  VM4();
  BAR();

  for (int tt = 0; tt < NT - 1; ++tt) {
    const int b = tt & 1, nb = b ^ 1;
    // P1: needs Ah0(t),Bh0(t) (landed: prev VM4+bar)
    P1_LOADS(b);
    STG_A(nb, 0, tt + 1);
    BAR(); LG0(); PRIO1(); MFMA16(0, 0, b01); PRIO0();
    VM4();  // lands Bh1(t) for P2
    BAR();
    // P2
    P2_LOADS(b);
    STG_B(nb, 0, tt + 1);
    BAR(); LG0(); PRIO1(); MFMA16(0, 2, b23); PRIO0();
    VM4();  // lands Ah1(t) for P3
    BAR();
    // P3
    P3_LOADS(b);
    STG_B(nb, 1, tt + 1);
    BAR(); LG0(); PRIO1(); MFMA16(4, 0, b01); PRIO0();
    BAR();
    // P4 (no ds reads)
    STG_A(nb, 1, tt + 1);
    BAR(); PRIO1(); MFMA16(4, 2, b23); PRIO0();
    VM4();  // lands Ah0,Bh0(t+1) for next P1
    BAR();
  }
  {  // last tile: no staging; drain with counted waits
    const int b = (NT - 1) & 1;
    P1_LOADS(b);
    BAR(); LG0(); PRIO1(); MFMA16(0, 0, b01); PRIO0();
    VM2();
    BAR();
    P2_LOADS(b);
    BAR(); LG0(); PRIO1(); MFMA16(0, 2, b23); PRIO0();
    VM0();
    BAR();
    P3_LOADS(b);
    BAR(); LG0(); PRIO1(); MFMA16(4, 0, b01); PRIO0();
    BAR();
    PRIO1(); MFMA16(4, 2, b23); PRIO0();
  }

#pragma unroll
  for (int m = 0; m < 8; m++)
#pragma unroll
    for (int n = 0; n < 4; n++)
#pragma unroll
      for (int r = 0; r < 4; r++) {
        size_t row = bm * 256 + m * 32 + wr * 16 + l4 * 4 + r;
        size_t col = bn * 256 + n * 64 + wc * 16 + l15;
        if (OUT_BF16)
          ((u16*)Cout)[row * N + col] = f2bf(acc[m][n][r]);
        else
          ((float*)Cout)[row * N + col] = acc[m][n][r];
      }
#undef STG_A
#undef STG_B
#undef LDA
#undef LDB
#undef P1_LOADS
#undef P2_LOADS
#undef P3_LOADS
#undef MFMA16
}

// ---------------- fused RMSNorm + RoPE + scale, in place on bf16 q/k ----------------
__global__ __launch_bounds__(128) void k_normrope(u16* __restrict__ qkv,
                                                  const int* __restrict__ pos_ids,
                                                  const float* __restrict__ qw,
                                                  const float* __restrict__ kw) {
  __shared__ float cross[2];
  int idx = blockIdx.x;
  int s = idx / 12, r = idx % 12;
  bool is_q = (r < 8);
  u16* p = qkv + (size_t)s * QKV_N + (is_q ? r * HD : 2048 + (r - 8) * HD);
  const float* w = is_q ? qw : kw;
  int j = threadIdx.x;  // 0..127
  float x1 = bf2f(p[j]), x2 = bf2f(p[j + 128]);
  float ss = x1 * x1 + x2 * x2;
#pragma unroll
  for (int off = 1; off < 64; off <<= 1) ss += __shfl_xor(ss, off);
  if ((threadIdx.x & 63) == 0) cross[threadIdx.x >> 6] = ss;
  __syncthreads();
  float rms = rsqrtf((cross[0] + cross[1]) * (1.0f / 256.0f) + 1e-6f);
  float y1 = x1 * rms * (1.0f + w[j]);
  float y2 = x2 * rms * (1.0f + w[j + 128]);
  float ang = (float)pos_ids[s] * exp2f((float)j * (-13.287712379549449f / 128.0f));
  float sn, c;
  sincosf(ang, &sn, &c);
  float sc = is_q ? QSCALE : 1.0f;
  p[j] = f2bf((y1 * c - y2 * sn) * sc);
  p[j + 128] = f2bf((y1 * sn + y2 * c) * sc);
}

// ---------------- flash attention v5: sliding window, GQA-shared K/V ----------------
// block = (64 q x 1 kv-head), 8 waves: wave w -> head kvh*2+(w>>2), rows q0+(w&3)*16.
// K,V single-buffered in LDS (32KB+32KB) + lP 16KB = 80KB -> 2 blocks/CU, 4 waves/SIMD.
// Staging via gld_lds w/ pre-swizzled src; XOR (row&7)<<4 swizzle on all strided reads.
__global__ __launch_bounds__(512, 4) void k_attn(const u16* __restrict__ qkv,
                                                 const u16* __restrict__ vt,
                                                 const int* __restrict__ pos_ids,
                                                 u16* __restrict__ aout) {
  __shared__ u16 lK[64 * 256];   // [key][d], rows 512B, swizzled
  __shared__ u16 lV[256 * 64];   // [d][key], rows 128B, swizzled
  __shared__ u16 lP[8][16 * 64]; // per-wave P, rows 128B, swizzled
  const int bid = blockIdx.x;    // 256 blocks
  const int wg = (bid & 7) * 32 + (bid >> 3);  // bijective XCD swizzle
  const int kvh = wg >> 6;                     // 0..3
  const int q0 = (wg & 63) * 64;               // 0..4032
  const int t = threadIdx.x, lane = t & 63, wave = t >> 6;
  const int l15 = lane & 15, l4 = lane >> 4;
  const int head = kvh * 2 + (wave >> 2);
  const int qw = q0 + (wave & 3) * 16;

  bf16x8 qfr[8];
  {
    const u16* qptr = qkv + (size_t)(qw + l15) * QKV_N + head * HD + l4 * 8;
#pragma unroll
    for (int kc = 0; kc < 8; kc++) qfr[kc] = *(const bf16x8*)(qptr + kc * 32);
  }
  f32x4 acc[16] = {};
  float mrow[4], lrow[4];
#pragma unroll
  for (int r = 0; r < 4; r++) { mrow[r] = -1e30f; lrow[r] = 0.0f; }
  int qi[4];
#pragma unroll
  for (int r = 0; r < 4; r++) qi[r] = pos_ids[qw + l4 * 4 + r];

  // staging: K chunk=1KB=2 rows x 512B; V chunk=1KB=8 rows x 128B; 4 of each per wave
  const int krw = lane >> 5, kcl = lane & 31;
  const int vrw = lane >> 3, vcl = lane & 7;
  const u16* kgb = qkv + 2048 + kvh * HD;
  const u16* vgb = vt + (size_t)kvh * HD * S_LEN;

  int start = q0 - (WIN - 1);
  if (start < 0) start = 0;
  start &= ~63;

#define STAGE_KV(T0) do {                                                             \
    _Pragma("unroll")                                                                 \
    for (int i_ = 0; i_ < 4; i_++) {                                                  \
      int ch_ = wave * 4 + i_;                                                        \
      int kr_ = ch_ * 2 + krw;                                                        \
      gld16(kgb + (size_t)((T0) + kr_) * QKV_N + ((kcl ^ (kr_ & 7)) * 8),             \
            &lK[ch_ * 512]);                                                          \
      int vr_ = ch_ * 8 + vrw;                                                        \
      gld16(vgb + (size_t)vr_ * S_LEN + (T0) + ((vcl ^ (vr_ & 7)) * 8),               \
            &lV[ch_ * 512]);                                                          \
    }                                                                                 \
  } while (0)

  for (int t0 = start; t0 <= q0 + 63; t0 += 64) {
    STAGE_KV(t0);
    int kp[4];
#pragma unroll
    for (int kb = 0; kb < 4; kb++) kp[kb] = pos_ids[t0 + kb * 16 + l15];
    __syncthreads();
    f32x4 sv[4] = {};
    PRIO1();
#pragma unroll
    for (int kb = 0; kb < 4; kb++) {
      const char* krow = (const char*)&lK[(kb * 16 + l15) * 256];
      const int sw = ((kb * 16 + l15) & 7) << 4;
#pragma unroll
      for (int kc = 0; kc < 8; kc++) {
        bf16x8 kf = *(const bf16x8*)(krow + ((kc * 64 + l4 * 16) ^ sw));
        sv[kb] = __builtin_amdgcn_mfma_f32_16x16x32_bf16(qfr[kc], kf, sv[kb], 0, 0, 0);
      }
    }
    PRIO0();
    float sloc[4][4], mx[4];
    float need = 0.0f;
#pragma unroll
    for (int r = 0; r < 4; r++) {
      int pi = qi[r];
#pragma unroll
      for (int kb = 0; kb < 4; kb++)
        sloc[r][kb] = ((kp[kb] <= pi) && (pi - kp[kb] < WIN)) ? sv[kb][r] : -__builtin_inff();
      float m_ = fmaxf(fmaxf(sloc[r][0], sloc[r][1]), fmaxf(sloc[r][2], sloc[r][3]));
#pragma unroll
      for (int off = 1; off < 16; off <<= 1) m_ = fmaxf(m_, __shfl_xor(m_, off));
      mx[r] = m_;
      need = fmaxf(need, m_ - mrow[r]);
    }
    bool resc = __any(need > 8.0f);
    if (resc) {
#pragma unroll
      for (int r = 0; r < 4; r++) {
        float nm = fmaxf(mrow[r], mx[r]);
        float al = __expf(mrow[r] - nm);
        mrow[r] = nm;
        lrow[r] *= al;
#pragma unroll
        for (int nd = 0; nd < 16; nd++) acc[nd][r] *= al;
      }
    }
#pragma unroll
    for (int r = 0; r < 4; r++) {
      float nm = mrow[r];
      float e0 = __expf(sloc[r][0] - nm), e1 = __expf(sloc[r][1] - nm);
      float e2 = __expf(sloc[r][2] - nm), e3 = __expf(sloc[r][3] - nm);
      float sum = (e0 + e1) + (e2 + e3);
#pragma unroll
      for (int off = 1; off < 16; off <<= 1) sum += __shfl_xor(sum, off);
      lrow[r] += sum;
      int q = l4 * 4 + r;
      char* lpw = (char*)&lP[wave][0] + q * 128;
      int swp = (q & 7) << 4;
      *(u16*)(lpw + ((l15 * 2) ^ swp)) = f2bf(e0);
      *(u16*)(lpw + ((32 + l15 * 2) ^ swp)) = f2bf(e1);
      *(u16*)(lpw + ((64 + l15 * 2) ^ swp)) = f2bf(e2);
      *(u16*)(lpw + ((96 + l15 * 2) ^ swp)) = f2bf(e3);
    }
#pragma unroll
    for (int kc2 = 0; kc2 < 2; kc2++) {
      int q = l15;
      bf16x8 pa = *(const bf16x8*)((const char*)&lP[wave][0] + q * 128 +
                                   ((kc2 * 64 + l4 * 16) ^ ((q & 7) << 4)));
      PRIO1();
#pragma unroll
      for (int nd = 0; nd < 16; nd++) {
        int d = nd * 16 + l15;
        bf16x8 vf = *(const bf16x8*)((const char*)&lV[d * 64] +
                                     ((kc2 * 64 + l4 * 16) ^ ((d & 7) << 4)));
        acc[nd] = __builtin_amdgcn_mfma_f32_16x16x32_bf16(pa, vf, acc[nd], 0, 0, 0);
      }
      PRIO0();
    }
    __syncthreads();
  }
  float rinv[4];
#pragma unroll
  for (int r = 0; r < 4; r++) rinv[r] = 1.0f / lrow[r];
#pragma unroll
  for (int nd = 0; nd < 16; nd++)
#pragma unroll
    for (int r = 0; r < 4; r++) {
      size_t row = qw + l4 * 4 + r;
      aout[row * AO_N + head * HD + nd * 16 + l15] = f2bf(acc[nd][r] * rinv[r]);
    }
#undef STAGE_KV
}

extern "C" void kernel_launch(void* const* d_in, const int* in_sizes, int n_in,
                              void* d_out, int out_size, void* d_ws, size_t ws_size,
                              hipStream_t stream) {
  const float* x = (const float*)d_in[0];
  const int* pos = (const int*)d_in[1];
  const float* wq = (const float*)d_in[2];
  const float* wk = (const float*)d_in[3];
  const float* wv = (const float*)d_in[4];
  const float* wo = (const float*)d_in[5];
  const float* qnw = (const float*)d_in[6];
  const float* knw = (const float*)d_in[7];

  // scratch layout:
  //   d_out: qkv bf16 [4096][4096] (overwritten by final fp32 GEMM)
  //   ws+0        : x bf16 [4096][2304]; later aout bf16 [4096][2048]
  //   ws+18874368 : W^T bf16 (qkv-phase: [4096][2304]; out-phase: wo^T [2304][2048])
  //   ws+28311552 : vt bf16 [4][256][4096]
  u16* qkv = (u16*)d_out;
  u16* xbf = (u16*)d_ws;
  u16* wT = (u16*)((char*)d_ws + 18874368);
  u16* vtb = (u16*)((char*)d_ws + 28311552);
  u16* aout = xbf;

  k_cvt_bf16<<<9216, 256, 0, stream>>>(x, xbf, S_LEN * HID_DIM);
  k_transpose_cvt<<<dim3(64, 72), 256, 0, stream>>>(wq, 2048, wT, HID_DIM, 0);
  k_transpose_cvt<<<dim3(32, 72), 256, 0, stream>>>(wk, 1024, wT, HID_DIM, 2048);
  k_transpose_cvt<<<dim3(32, 72), 256, 0, stream>>>(wv, 1024, wT, HID_DIM, 3072);
  k_gemm8p<1><<<dim3(256), 512, 0, stream>>>(xbf, wT, qkv, S_LEN, QKV_N, HID_DIM);
  k_vtrans<<<dim3(32, 128), 256, 0, stream>>>(qkv, vtb);
  k_normrope<<<S_LEN * 12, 128, 0, stream>>>(qkv, pos, qnw, knw);
  k_attn<<<dim3(256), 512, 0, stream>>>(qkv, vtb, pos, aout);
  k_transpose_cvt<<<dim3(72, 64), 256, 0, stream>>>(wo, HID_DIM, wT, 2048, 0);
  k_gemm8p<0><<<dim3(144), 512, 0, stream>>>(aout, wT, d_out, S_LEN, HID_DIM, 2048);
}

// Round 7
// 266.571 us; speedup vs baseline: 1.7549x; 1.7549x over previous
//
#include <hip/hip_runtime.h>
#include <stdint.h>

typedef unsigned short u16;
typedef __attribute__((ext_vector_type(8))) short bf16x8;
typedef __attribute__((ext_vector_type(4))) float f32x4;

#define S_LEN 4096
#define HID_DIM 2304
#define QKV_N 4096
#define AO_N 2048
#define HD 256
#define WIN 1024
#define QSCALE 0.0625f

static __device__ __forceinline__ u16 f2bf(float f) {
  union { float f; uint32_t u; } v; v.f = f;
  return (u16)((v.u + 0x7FFFu + ((v.u >> 16) & 1u)) >> 16);
}
static __device__ __forceinline__ float bf2f(u16 h) {
  union { uint32_t u; float f; } v; v.u = ((uint32_t)h) << 16;
  return v.f;
}

static __device__ __forceinline__ void gld16(const void* src, void* dst) {
  __builtin_amdgcn_global_load_lds((const __attribute__((address_space(1))) void*)src,
                                   (__attribute__((address_space(3))) void*)dst, 16, 0, 0);
}

#define BAR() __builtin_amdgcn_s_barrier()
#define LG0() asm volatile("s_waitcnt lgkmcnt(0)" ::: "memory")
#define VM4() asm volatile("s_waitcnt vmcnt(4)" ::: "memory")
#define VM2() asm volatile("s_waitcnt vmcnt(2)" ::: "memory")
#define VM0() asm volatile("s_waitcnt vmcnt(0)" ::: "memory")
#define PRIO1() __builtin_amdgcn_s_setprio(1)
#define PRIO0() __builtin_amdgcn_s_setprio(0)

// ---------------- fp32 -> bf16 elementwise ----------------
__global__ __launch_bounds__(256) void k_cvt_bf16(const float* __restrict__ in,
                                                  u16* __restrict__ out, int n) {
  int i = (blockIdx.x * 256 + threadIdx.x) * 4;
  if (i >= n) return;
  float4 v = *(const float4*)(in + i);
  uint64_t p = (uint64_t)f2bf(v.x) | ((uint64_t)f2bf(v.y) << 16)
             | ((uint64_t)f2bf(v.z) << 32) | ((uint64_t)f2bf(v.w) << 48);
  *(uint64_t*)(out + i) = p;
}

// in: fp32 [R][C] row-major; out bf16: out[(row_off + c)*out_stride + r] = in[r][c]
__global__ __launch_bounds__(256) void k_transpose_cvt(const float* __restrict__ in, int C,
                                                       u16* __restrict__ out, int out_stride,
                                                       int row_off) {
  __shared__ float tile[32][33];
  int c0 = blockIdx.x * 32, r0 = blockIdx.y * 32;
  int tx = threadIdx.x & 31, ty = threadIdx.x >> 5;
#pragma unroll
  for (int i = 0; i < 4; i++)
    tile[ty + i * 8][tx] = in[(size_t)(r0 + ty + i * 8) * C + c0 + tx];
  __syncthreads();
#pragma unroll
  for (int i = 0; i < 4; i++)
    out[(size_t)(row_off + c0 + ty + i * 8) * out_stride + r0 + tx] = f2bf(tile[tx][ty + i * 8]);
}

// ---------------- bf16 transpose of V block of qkv -> vt[kv*256 + d][s] ----------------
__global__ __launch_bounds__(256) void k_vtrans(const u16* __restrict__ qkv,
                                                u16* __restrict__ vtout) {
  __shared__ u16 tile[32][33];
  int c0 = blockIdx.x * 32, s0 = blockIdx.y * 32;
  int tx = threadIdx.x & 31, ty = threadIdx.x >> 5;
#pragma unroll
  for (int i = 0; i < 4; i++)
    tile[ty + i * 8][tx] = qkv[(size_t)(s0 + ty + i * 8) * QKV_N + 3072 + c0 + tx];
  __syncthreads();
#pragma unroll
  for (int i = 0; i < 4; i++)
    vtout[(size_t)(c0 + ty + i * 8) * S_LEN + s0 + tx] = tile[tx][ty + i * 8];
}

// ---------------- bf16 GEMM v3: 256x256, BK=64, true 8-phase (m201 structure) ------------
// 8 waves (2Mx4N) with INTERLEAVED tiling: A row(m)=m*32+wr*16+l15, B row(n)=n*64+wc*16+l15
// so phase operands live in one half-tile. Per K-tile: 4 phases x {ds_reads; stage one
// half-tile of tile t+1 (2 gld16, pre-swizzled src); barrier; lgkm0; prio1; 16 MFMA; prio0;
// counted vmcnt before closing barrier}. Stage order Ah0,Bh0,Bh1,Ah1 = consumption order;
// steady-state vmcnt(4), never drains. LDS 2dbuf x (A+B) 64KB = 128KB.
template <int OUT_BF16>
__global__ __launch_bounds__(512, 2) void k_gemm8p(const u16* __restrict__ A,
                                                   const u16* __restrict__ Bt,
                                                   void* __restrict__ Cout,
                                                   int M, int N, int K) {
  __shared__ u16 sA[2][256 * 64];
  __shared__ u16 sB[2][256 * 64];
  const int t = threadIdx.x, lane = t & 63, wave = t >> 6;
  const int wr = wave >> 2, wc = wave & 3;
  const int l15 = lane & 15, l4 = lane >> 4;
  const int nbn = N >> 8;
  const int cpx = gridDim.x >> 3;
  const int wg = ((int)blockIdx.x & 7) * cpx + ((int)blockIdx.x >> 3);  // bijective XCD swz
  const int bm = wg / nbn, bn = wg % nbn;
  const int NT = K >> 6;
  // staging lane map: half-tile = 128 rows x 128B; per gld16 a wave covers 8 rows x 128B;
  // lane -> row = lane>>3, slot = lane&7; src slot pre-swizzled (involution slot^(row&7))
  const int srow = lane >> 3;
  const int sslot = ((lane & 7) ^ srow) * 8;
  const u16* Abase = A + (size_t)(bm * 256) * K;
  const u16* Bbase = Bt + (size_t)(bn * 256) * K;
  f32x4 acc[8][4] = {};
  bf16x8 aF[4][2], b01[2][2], b23[2][2];

#define STG_A(BUF, HALF, KT) do {                                                 \
    _Pragma("unroll")                                                             \
    for (int c_ = 0; c_ < 2; c_++) {                                              \
      int rb_ = (HALF) * 128 + (wave * 2 + c_) * 8;                               \
      gld16(Abase + (size_t)(rb_ + srow) * K + ((KT) << 6) + sslot,               \
            &sA[BUF][rb_ * 64]);                                                  \
    }                                                                             \
  } while (0)
#define STG_B(BUF, HALF, KT) do {                                                 \
    _Pragma("unroll")                                                             \
    for (int c_ = 0; c_ < 2; c_++) {                                              \
      int rb_ = (HALF) * 128 + (wave * 2 + c_) * 8;                               \
      gld16(Bbase + (size_t)(rb_ + srow) * K + ((KT) << 6) + sslot,               \
            &sB[BUF][rb_ * 64]);                                                  \
    }                                                                             \
  } while (0)
// LDS read with matching XOR swizzle; row&7 == l15&7 for all frag rows
#define LDA(BUF, M_, KK)                                                          \
  (*(const bf16x8*)&sA[BUF][((M_) * 32 + wr * 16 + l15) * 64 +                    \
                            ((((KK) << 2) + l4) ^ (l15 & 7)) * 8])
#define LDB(BUF, N_, KK)                                                          \
  (*(const bf16x8*)&sB[BUF][((N_) * 64 + wc * 16 + l15) * 64 +                    \
                            ((((KK) << 2) + l4) ^ (l15 & 7)) * 8])

#define P1_LOADS(b_) do {                                                         \
    _Pragma("unroll") for (int m_ = 0; m_ < 4; m_++)                              \
      _Pragma("unroll") for (int k_ = 0; k_ < 2; k_++)                            \
        aF[m_][k_] = LDA(b_, m_, k_);                                             \
    _Pragma("unroll") for (int n_ = 0; n_ < 2; n_++)                              \
      _Pragma("unroll") for (int k_ = 0; k_ < 2; k_++)                            \
        b01[n_][k_] = LDB(b_, n_, k_);                                            \
  } while (0)
#define P2_LOADS(b_) do {                                                         \
    _Pragma("unroll") for (int n_ = 0; n_ < 2; n_++)                              \
      _Pragma("unroll") for (int k_ = 0; k_ < 2; k_++)                            \
        b23[n_][k_] = LDB(b_, n_ + 2, k_);                                        \
  } while (0)
#define P3_LOADS(b_) do {                                                         \
    _Pragma("unroll") for (int m_ = 0; m_ < 4; m_++)                              \
      _Pragma("unroll") for (int k_ = 0; k_ < 2; k_++)                            \
        aF[m_][k_] = LDA(b_, m_ + 4, k_);                                         \
  } while (0)
#define MFMA16(MOFF, NOFF, BREG) do {                                             \
    _Pragma("unroll") for (int m_ = 0; m_ < 4; m_++)                              \
      _Pragma("unroll") for (int n_ = 0; n_ < 2; n_++)                            \
        _Pragma("unroll") for (int k_ = 0; k_ < 2; k_++)                          \
          acc[m_ + MOFF][n_ + NOFF] = __builtin_amdgcn_mfma_f32_16x16x32_bf16(    \
              aF[m_][k_], BREG[n_][k_], acc[m_ + MOFF][n_ + NOFF], 0, 0, 0);      \
  } while (0)

  // prologue: stage tile 0 in consumption order
  STG_A(0, 0, 0);
  STG_B(0, 0, 0);
  STG_B(0, 1, 0);
  STG_A(0, 1, 0);
  VM4();
  BAR();

  for (int tt = 0; tt < NT - 1; ++tt) {
    const int b = tt & 1, nb = b ^ 1;
    // P1: needs Ah0(t),Bh0(t) (landed: prev VM4+bar)
    P1_LOADS(b);
    STG_A(nb, 0, tt + 1);
    BAR(); LG0(); PRIO1(); MFMA16(0, 0, b01); PRIO0();
    VM4();  // lands Bh1(t) for P2
    BAR();
    // P2
    P2_LOADS(b);
    STG_B(nb, 0, tt + 1);
    BAR(); LG0(); PRIO1(); MFMA16(0, 2, b23); PRIO0();
    VM4();  // lands Ah1(t) for P3
    BAR();
    // P3
    P3_LOADS(b);
    STG_B(nb, 1, tt + 1);
    BAR(); LG0(); PRIO1(); MFMA16(4, 0, b01); PRIO0();
    BAR();
    // P4 (no ds reads)
    STG_A(nb, 1, tt + 1);
    BAR(); PRIO1(); MFMA16(4, 2, b23); PRIO0();
    VM4();  // lands Ah0,Bh0(t+1) for next P1
    BAR();
  }
  {  // last tile: no staging; drain with counted waits
    const int b = (NT - 1) & 1;
    P1_LOADS(b);
    BAR(); LG0(); PRIO1(); MFMA16(0, 0, b01); PRIO0();
    VM2();
    BAR();
    P2_LOADS(b);
    BAR(); LG0(); PRIO1(); MFMA16(0, 2, b23); PRIO0();
    VM0();
    BAR();
    P3_LOADS(b);
    BAR(); LG0(); PRIO1(); MFMA16(4, 0, b01); PRIO0();
    BAR();
    PRIO1(); MFMA16(4, 2, b23); PRIO0();
  }

#pragma unroll
  for (int m = 0; m < 8; m++)
#pragma unroll
    for (int n = 0; n < 4; n++)
#pragma unroll
      for (int r = 0; r < 4; r++) {
        size_t row = bm * 256 + m * 32 + wr * 16 + l4 * 4 + r;
        size_t col = bn * 256 + n * 64 + wc * 16 + l15;
        if (OUT_BF16)
          ((u16*)Cout)[row * N + col] = f2bf(acc[m][n][r]);
        else
          ((float*)Cout)[row * N + col] = acc[m][n][r];
      }
#undef STG_A
#undef STG_B
#undef LDA
#undef LDB
#undef P1_LOADS
#undef P2_LOADS
#undef P3_LOADS
#undef MFMA16
}

// ---------------- fused RMSNorm + RoPE + scale, in place on bf16 q/k ----------------
__global__ __launch_bounds__(128) void k_normrope(u16* __restrict__ qkv,
                                                  const int* __restrict__ pos_ids,
                                                  const float* __restrict__ qw,
                                                  const float* __restrict__ kw) {
  __shared__ float cross[2];
  int idx = blockIdx.x;
  int s = idx / 12, r = idx % 12;
  bool is_q = (r < 8);
  u16* p = qkv + (size_t)s * QKV_N + (is_q ? r * HD : 2048 + (r - 8) * HD);
  const float* w = is_q ? qw : kw;
  int j = threadIdx.x;  // 0..127
  float x1 = bf2f(p[j]), x2 = bf2f(p[j + 128]);
  float ss = x1 * x1 + x2 * x2;
#pragma unroll
  for (int off = 1; off < 64; off <<= 1) ss += __shfl_xor(ss, off);
  if ((threadIdx.x & 63) == 0) cross[threadIdx.x >> 6] = ss;
  __syncthreads();
  float rms = rsqrtf((cross[0] + cross[1]) * (1.0f / 256.0f) + 1e-6f);
  float y1 = x1 * rms * (1.0f + w[j]);
  float y2 = x2 * rms * (1.0f + w[j + 128]);
  float ang = (float)pos_ids[s] * exp2f((float)j * (-13.287712379549449f / 128.0f));
  float sn, c;
  sincosf(ang, &sn, &c);
  float sc = is_q ? QSCALE : 1.0f;
  p[j] = f2bf((y1 * c - y2 * sn) * sc);
  p[j + 128] = f2bf((y1 * sn + y2 * c) * sc);
}

// ---------------- flash attention v4 (R5-proven): sliding window, GQA-shared K/V --------
// block = (32 q x 1 kv-head, BOTH q-heads): wave w -> head kvh*2+(w>>1), rows q0+(w&1)*16.
// K,V single-buffered in LDS (32KB+32KB, gld_lds pre-swizzled src, XOR (row&7)<<4 reads),
// lP 8KB -> 72KB total -> 2 blocks/CU (2 waves/SIMD). Grid 512, bijective XCD swizzle.
__global__ __launch_bounds__(256, 2) void k_attn(const u16* __restrict__ qkv,
                                                 const u16* __restrict__ vt,
                                                 const int* __restrict__ pos_ids,
                                                 u16* __restrict__ aout) {
  __shared__ u16 lK[64 * 256];   // [key][d], rows 512B, swizzled
  __shared__ u16 lV[256 * 64];   // [d][key], rows 128B, swizzled
  __shared__ u16 lP[4][16 * 64]; // per-wave P, rows 128B, swizzled
  const int bid = blockIdx.x;
  const int wg = (bid & 7) * 64 + (bid >> 3);
  const int kvh = wg >> 7;
  const int q0 = (wg & 127) * 32;
  const int t = threadIdx.x, lane = t & 63, wave = t >> 6;
  const int l15 = lane & 15, l4 = lane >> 4;
  const int head = kvh * 2 + (wave >> 1);
  const int qw = q0 + (wave & 1) * 16;

  bf16x8 qfr[8];
  {
    const u16* qptr = qkv + (size_t)(qw + l15) * QKV_N + head * HD + l4 * 8;
#pragma unroll
    for (int kc = 0; kc < 8; kc++) qfr[kc] = *(const bf16x8*)(qptr + kc * 32);
  }
  f32x4 acc[16] = {};
  float mrow[4], lrow[4];
#pragma unroll
  for (int r = 0; r < 4; r++) { mrow[r] = -1e30f; lrow[r] = 0.0f; }
  int qi[4];
#pragma unroll
  for (int r = 0; r < 4; r++) qi[r] = pos_ids[qw + l4 * 4 + r];

  const int krw = lane >> 5, kcl = lane & 31;
  const int vrw = lane >> 3, vcl = lane & 7;
  const u16* kgb = qkv + 2048 + kvh * HD;
  const u16* vgb = vt + (size_t)kvh * HD * S_LEN;

  int start = q0 - (WIN - 1);
  if (start < 0) start = 0;
  start &= ~63;

#define STAGE_KV(T0) do {                                                             \
    _Pragma("unroll")                                                                 \
    for (int i_ = 0; i_ < 8; i_++) {                                                  \
      int ch_ = wave * 8 + i_;                                                        \
      int kr_ = ch_ * 2 + krw;                                                        \
      gld16(kgb + (size_t)((T0) + kr_) * QKV_N + ((kcl ^ (kr_ & 7)) * 8),             \
            &lK[ch_ * 512]);                                                          \
      int vr_ = ch_ * 8 + vrw;                                                        \
      gld16(vgb + (size_t)vr_ * S_LEN + (T0) + ((vcl ^ (vr_ & 7)) * 8),               \
            &lV[ch_ * 512]);                                                          \
    }                                                                                 \
  } while (0)

  for (int t0 = start; t0 <= q0 + 31; t0 += 64) {
    STAGE_KV(t0);
    int kp[4];
#pragma unroll
    for (int kb = 0; kb < 4; kb++) kp[kb] = pos_ids[t0 + kb * 16 + l15];
    __syncthreads();
    f32x4 sv[4] = {};
    PRIO1();
#pragma unroll
    for (int kb = 0; kb < 4; kb++) {
      const char* krow = (const char*)&lK[(kb * 16 + l15) * 256];
      const int sw = ((kb * 16 + l15) & 7) << 4;
#pragma unroll
      for (int kc = 0; kc < 8; kc++) {
        bf16x8 kf = *(const bf16x8*)(krow + ((kc * 64 + l4 * 16) ^ sw));
        sv[kb] = __builtin_amdgcn_mfma_f32_16x16x32_bf16(qfr[kc], kf, sv[kb], 0, 0, 0);
      }
    }
    PRIO0();
    float sloc[4][4], mx[4];
    float need = 0.0f;
#pragma unroll
    for (int r = 0; r < 4; r++) {
      int pi = qi[r];
#pragma unroll
      for (int kb = 0; kb < 4; kb++)
        sloc[r][kb] = ((kp[kb] <= pi) && (pi - kp[kb] < WIN)) ? sv[kb][r] : -__builtin_inff();
      float m_ = fmaxf(fmaxf(sloc[r][0], sloc[r][1]), fmaxf(sloc[r][2], sloc[r][3]));
#pragma unroll
      for (int off = 1; off < 16; off <<= 1) m_ = fmaxf(m_, __shfl_xor(m_, off));
      mx[r] = m_;
      need = fmaxf(need, m_ - mrow[r]);
    }
    bool resc = __any(need > 8.0f);
    if (resc) {
#pragma unroll
      for (int r = 0; r < 4; r++) {
        float nm = fmaxf(mrow[r], mx[r]);
        float al = __expf(mrow[r] - nm);
        mrow[r] = nm;
        lrow[r] *= al;
#pragma unroll
        for (int nd = 0; nd < 16; nd++) acc[nd][r] *= al;
      }
    }
#pragma unroll
    for (int r = 0; r < 4; r++) {
      float nm = mrow[r];
      float e0 = __expf(sloc[r][0] - nm), e1 = __expf(sloc[r][1] - nm);
      float e2 = __expf(sloc[r][2] - nm), e3 = __expf(sloc[r][3] - nm);
      float sum = (e0 + e1) + (e2 + e3);
#pragma unroll
      for (int off = 1; off < 16; off <<= 1) sum += __shfl_xor(sum, off);
      lrow[r] += sum;
      int q = l4 * 4 + r;
      char* lpw = (char*)&lP[wave][0] + q * 128;
      int swp = (q & 7) << 4;
      *(u16*)(lpw + ((l15 * 2) ^ swp)) = f2bf(e0);
      *(u16*)(lpw + ((32 + l15 * 2) ^ swp)) = f2bf(e1);
      *(u16*)(lpw + ((64 + l15 * 2) ^ swp)) = f2bf(e2);
      *(u16*)(lpw + ((96 + l15 * 2) ^ swp)) = f2bf(e3);
    }
#pragma unroll
    for (int kc2 = 0; kc2 < 2; kc2++) {
      int q = l15;
      bf16x8 pa = *(const bf16x8*)((const char*)&lP[wave][0] + q * 128 +
                                   ((kc2 * 64 + l4 * 16) ^ ((q & 7) << 4)));
      PRIO1();
#pragma unroll
      for (int nd = 0; nd < 16; nd++) {
        int d = nd * 16 + l15;
        bf16x8 vf = *(const bf16x8*)((const char*)&lV[d * 64] +
                                     ((kc2 * 64 + l4 * 16) ^ ((d & 7) << 4)));
        acc[nd] = __builtin_amdgcn_mfma_f32_16x16x32_bf16(pa, vf, acc[nd], 0, 0, 0);
      }
      PRIO0();
    }
    __syncthreads();
  }
  float rinv[4];
#pragma unroll
  for (int r = 0; r < 4; r++) rinv[r] = 1.0f / lrow[r];
#pragma unroll
  for (int nd = 0; nd < 16; nd++)
#pragma unroll
    for (int r = 0; r < 4; r++) {
      size_t row = qw + l4 * 4 + r;
      aout[row * AO_N + head * HD + nd * 16 + l15] = f2bf(acc[nd][r] * rinv[r]);
    }
#undef STAGE_KV
}

extern "C" void kernel_launch(void* const* d_in, const int* in_sizes, int n_in,
                              void* d_out, int out_size, void* d_ws, size_t ws_size,
                              hipStream_t stream) {
  const float* x = (const float*)d_in[0];
  const int* pos = (const int*)d_in[1];
  const float* wq = (const float*)d_in[2];
  const float* wk = (const float*)d_in[3];
  const float* wv = (const float*)d_in[4];
  const float* wo = (const float*)d_in[5];
  const float* qnw = (const float*)d_in[6];
  const float* knw = (const float*)d_in[7];

  // scratch layout:
  //   d_out: qkv bf16 [4096][4096] (overwritten by final fp32 GEMM)
  //   ws+0        : x bf16 [4096][2304]; later aout bf16 [4096][2048]
  //   ws+18874368 : W^T bf16 (qkv-phase: [4096][2304]; out-phase: wo^T [2304][2048])
  //   ws+28311552 : vt bf16 [4][256][4096]
  u16* qkv = (u16*)d_out;
  u16* xbf = (u16*)d_ws;
  u16* wT = (u16*)((char*)d_ws + 18874368);
  u16* vtb = (u16*)((char*)d_ws + 28311552);
  u16* aout = xbf;

  k_cvt_bf16<<<9216, 256, 0, stream>>>(x, xbf, S_LEN * HID_DIM);
  k_transpose_cvt<<<dim3(64, 72), 256, 0, stream>>>(wq, 2048, wT, HID_DIM, 0);
  k_transpose_cvt<<<dim3(32, 72), 256, 0, stream>>>(wk, 1024, wT, HID_DIM, 2048);
  k_transpose_cvt<<<dim3(32, 72), 256, 0, stream>>>(wv, 1024, wT, HID_DIM, 3072);
  k_gemm8p<1><<<dim3(256), 512, 0, stream>>>(xbf, wT, qkv, S_LEN, QKV_N, HID_DIM);
  k_vtrans<<<dim3(32, 128), 256, 0, stream>>>(qkv, vtb);
  k_normrope<<<S_LEN * 12, 128, 0, stream>>>(qkv, pos, qnw, knw);
  k_attn<<<dim3(512), 256, 0, stream>>>(qkv, vtb, pos, aout);
  k_transpose_cvt<<<dim3(72, 64), 256, 0, stream>>>(wo, HID_DIM, wT, 2048, 0);
  k_gemm8p<0><<<dim3(144), 512, 0, stream>>>(aout, wT, d_out, S_LEN, HID_DIM, 2048);
}